// Round 9
// baseline (85.610 us; speedup 1.0000x reference)
//
#include <hip/hip_runtime.h>

#define N 64
#define MARGIN 0.1f
#define WAVES_PER_BLOCK 4
#define NBLOCKS 2048

// closed form (verified R2..R8, absmax 0.0): row_loss = sum_e u_e*(q_e - p_e)
//   p_e = #{k: lab_k < lab_e},  u_e = sc_e - MARGIN*p_e,  q_e = #{k: u_k < u_e}
//
// R9: pipe balance. Per-CU model for R8 showed the single LDS pipe (shared by
// 4 SIMDs) binding at ~11 us (17 LDS ops/row) while VALU ~7 us, SMEM ~3.4 us.
// Split pass-2 supply: elems 0..31 from LDS (8 ds_read_b128), elems 32..63
// via v_readlane (VALU). Pass-1 stays on SMEM (s_load_dwordx4).
__global__ __launch_bounds__(256) void mmrl_partial(const float* __restrict__ scores,
                                                    const float* __restrict__ labels,
                                                    float* __restrict__ partial,
                                                    int rows) {
    __shared__ float ubuf[WAVES_PER_BLOCK][N];
    __shared__ float wsum[WAVES_PER_BLOCK];

    const int lane = threadIdx.x & 63;
    const int w    = threadIdx.x >> 6;
    const int gwave = blockIdx.x * WAVES_PER_BLOCK + w;
    const int nwaves = NBLOCKS * WAVES_PER_BLOCK;

    float acc = 0.0f;

    for (int row = gwave; row < rows; row += nwaves) {
        const int base = __builtin_amdgcn_readfirstlane(row) * N;
        const float labv = labels[base + lane];   // coalesced per-lane copy
        const float scv  = scores[base + lane];

        // ---- pass 1: label rank p (SMEM float4 broadcasts) ----
        const float4* L4 = (const float4*)(labels + base);
        int p0 = 0, p1 = 0, p2 = 0, p3 = 0;
        #pragma unroll
        for (int kk = 0; kk < N / 4; ++kk) {
            const float4 a = L4[kk];
            p0 += (a.x < labv);
            p1 += (a.y < labv);
            p2 += (a.z < labv);
            p3 += (a.w < labv);
        }
        const int pv = (p0 + p1) + (p2 + p3);

        const float u = fmaf(-MARGIN, (float)pv, scv);

        // ---- pass 2a: elems 0..31 via LDS uniform float4 broadcasts ----
        ubuf[w][lane] = u;
        asm volatile("s_waitcnt lgkmcnt(0)" ::: "memory");
        const float4* U4 = (const float4*)ubuf[w];
        int q0 = 0, q1 = 0, q2 = 0, q3 = 0;
        #pragma unroll
        for (int kk = 0; kk < 8; ++kk) {          // first 32 elements
            const float4 a = U4[kk];
            q0 += (a.x < u);
            q1 += (a.y < u);
            q2 += (a.z < u);
            q3 += (a.w < u);
        }

        // ---- pass 2b: elems 32..63 via v_readlane (VALU pipe) ----
        const int ub = __float_as_int(u);
        #pragma unroll
        for (int e = 32; e < 64; e += 4) {
            const float x0 = __int_as_float(__builtin_amdgcn_readlane(ub, e));
            const float x1 = __int_as_float(__builtin_amdgcn_readlane(ub, e + 1));
            const float x2 = __int_as_float(__builtin_amdgcn_readlane(ub, e + 2));
            const float x3 = __int_as_float(__builtin_amdgcn_readlane(ub, e + 3));
            q0 += (x0 < u);
            q1 += (x1 < u);
            q2 += (x2 < u);
            q3 += (x3 < u);
        }
        const int qv = (q0 + q1) + (q2 + q3);

        acc = fmaf(u, (float)(qv - pv), acc);
    }

    // ---- wave reduction ----
    #pragma unroll
    for (int off = 32; off > 0; off >>= 1)
        acc += __shfl_down(acc, off, 64);

    if (lane == 0) wsum[w] = acc;
    __syncthreads();
    if (threadIdx.x == 0) {
        float s = 0.0f;
        #pragma unroll
        for (int i = 0; i < WAVES_PER_BLOCK; ++i) s += wsum[i];
        partial[blockIdx.x] = s;          // plain store, no atomic
    }
}

__global__ __launch_bounds__(256) void mmrl_reduce(const float* __restrict__ partial,
                                                   float* __restrict__ out,
                                                   int npartial, float inv_rows) {
    const int t = threadIdx.x;
    float s = 0.0f;
    for (int i = t; i < npartial; i += 256)
        s += partial[i];
    #pragma unroll
    for (int off = 32; off > 0; off >>= 1)
        s += __shfl_down(s, off, 64);
    __shared__ float wsum[4];
    if ((t & 63) == 0) wsum[t >> 6] = s;
    __syncthreads();
    if (t == 0)
        out[0] = (wsum[0] + wsum[1] + wsum[2] + wsum[3]) * inv_rows;
}

extern "C" void kernel_launch(void* const* d_in, const int* in_sizes, int n_in,
                              void* d_out, int out_size, void* d_ws, size_t ws_size,
                              hipStream_t stream) {
    const float* scores = (const float*)d_in[0];
    const float* labels = (const float*)d_in[1];
    float* out = (float*)d_out;
    float* partial = (float*)d_ws;        // 2048 floats = 8 KB << ws_size
    const int rows = in_sizes[0] / N;     // 32768

    mmrl_partial<<<NBLOCKS, 256, 0, stream>>>(scores, labels, partial, rows);
    mmrl_reduce<<<1, 256, 0, stream>>>(partial, out, NBLOCKS, 1.0f / (float)rows);
}